// Round 11
// baseline (101.324 us; speedup 1.0000x reference)
//
#include <hip/hip_runtime.h>
#include <math.h>

// Problem shape (fixed by the reference): B=4, S=4, N=2048, D=2048
#define NB 4
#define NS 4
#define NN 2048
#define ND 2048
#define NTHREADS 1024
#define SQRT_D 45.254833995939045f   // sqrt(2048)

typedef float f32x4 __attribute__((ext_vector_type(4)));

// Compaction-butterfly ship, literal indices only (R3 lesson, R5/R7/R9-proven).
#define SHIP(I, H, M_) {                                      \
    const float keep_ = hi_ ? v[(I)+(H)] : v[(I)];            \
    const float give_ = hi_ ? v[(I)] : v[(I)+(H)];            \
    v[(I)] = keep_ + __shfl_xor(give_, (M_)); }

// 1024 threads: threads 0-511 own rows {0,1}, 512-1023 own rows {2,3},
// one f32x4 d-chunk each. Demand ~55 VGPR fits the 64 cap at (1024,8)
// -> 8 waves/SIMD, 2 blocks/CU (~100% occupancy). R8 failed this tier
// because 4-row ownership needed ~85 regs; 2-row ownership fits.
__global__ __launch_bounds__(NTHREADS, 8)
void hyperconn_kernel(const float* __restrict__ residuals,
                      const float* __restrict__ gamma,
                      const float* __restrict__ w_alpha,
                      const float* __restrict__ scale_alpha,
                      const float* __restrict__ static_alpha,
                      const float* __restrict__ w_beta,
                      const float* __restrict__ scale_beta,
                      const float* __restrict__ static_beta,
                      float* __restrict__ out)
{
    __shared__ float xex[NS][512][4];  // 32 KB: x exchange between thread-halves
    __shared__ float red[16][16];      // per-wave compacted sums (idx = brev4)
    __shared__ float asb[NS][6];       // [s][0..4]=alpha row, [s][5]=beta

    const int tid  = threadIdx.x;
    const int bn   = blockIdx.x;          // 0 .. NB*NN-1
    const int b    = bn >> 11;
    const int n    = bn & (NN - 1);
    const int wave = tid >> 6;
    const int lane = tid & 63;
    const int pair = tid >> 9;            // 0: rows {0,1}, 1: rows {2,3}
    const int c    = tid & 511;           // chunk id
    const int d    = c << 2;              // d-position of this thread's chunk

    const size_t row_stride = (size_t)NN * ND;
    const float* xbase = residuals + (size_t)(b * NS) * row_stride + (size_t)n * ND;
    float*       obase = out       + (size_t)(b * NS) * row_stride + (size_t)n * ND;

    // ---- Load this thread's 2 rows ----
    const float* rp = xbase + (size_t)(2 * pair) * row_stride + d;
    f32x4 xA = *(const f32x4*)(rp);
    f32x4 xB = *(const f32x4*)(rp + row_stride);

    // ---- Dots in fp32: v[0]=ssq(A); v[1..6]=dots A; v[7]=ssq(B); v[8..13]=dots B ----
    float v[16];
#pragma unroll
    for (int k = 0; k < 16; ++k) v[k] = 0.f;
    {
        f32x4 g4 = *(const f32x4*)(gamma + d);
#pragma unroll
        for (int e = 0; e < 4; ++e) {
            v[0] = __builtin_fmaf(xA[e], xA[e], v[0]);
            v[7] = __builtin_fmaf(xB[e], xB[e], v[7]);
        }
#pragma unroll
        for (int j = 0; j < 6; ++j) {
            const float* wsrc = (j < 5) ? (w_alpha + (size_t)j * ND + d)
                                        : (w_beta + d);
            f32x4 w4 = *(const f32x4*)wsrc;
            f32x4 wg = w4 + w4 * g4;       // w * (1 + gamma)
#pragma unroll
            for (int e = 0; e < 4; ++e) {
                v[1 + j] = __builtin_fmaf(xA[e], wg[e], v[1 + j]);
                v[8 + j] = __builtin_fmaf(xB[e], wg[e], v[8 + j]);
            }
        }
    }

    // ---- Publish own rows for the other half (visible after barrier 1) ----
    *(f32x4*)&xex[2 * pair][c][0]     = xA;
    *(f32x4*)&xex[2 * pair + 1][c][0] = xB;

    // ---- Compaction butterfly: 16 values in 15 ships + 2 xors ----
    { const bool hi_ = (lane & 1) != 0;
      SHIP(0,8,1) SHIP(1,8,1) SHIP(2,8,1) SHIP(3,8,1)
      SHIP(4,8,1) SHIP(5,8,1) SHIP(6,8,1) SHIP(7,8,1) }
    { const bool hi_ = (lane & 2) != 0;
      SHIP(0,4,2) SHIP(1,4,2) SHIP(2,4,2) SHIP(3,4,2) }
    { const bool hi_ = (lane & 4) != 0;
      SHIP(0,2,4) SHIP(1,2,4) }
    { const bool hi_ = (lane & 8) != 0;
      SHIP(0,1,8) }
    float tot = v[0] + __shfl_xor(v[0], 16);
    tot += __shfl_xor(tot, 32);
    // lane l<16 holds fully-reduced value brev4(l) (same family as R5's brev5)
    const int bidx = ((lane & 1) << 3) | ((lane & 2) << 1)
                   | ((lane & 4) >> 1) | ((lane & 8) >> 3);
    if (lane < 16) red[wave][bidx] = tot;
    __syncthreads();

    // ---- 24 threads: one tanh each. Rows 0,1 live in waves 0-7; rows 2,3 in 8-15 ----
    if (tid < 24) {
        const int s  = tid / 6;
        const int j  = tid % 6;
        const int wb = (s >> 1) * 8;       // wave base for this row
        const int rp_ = (s & 1) * 7;       // value offset within the 14
        float ssq = 0.f, dot = 0.f;
#pragma unroll
        for (int w = 0; w < 8; ++w) {
            ssq += red[wb + w][rp_];
            dot += red[wb + w][rp_ + 1 + j];
        }
        const float rs = SQRT_D / fmaxf(sqrtf(ssq), 1e-12f);
        const float th = tanhf(dot * rs);
        asb[s][j] = (j < 5) ? (th * scale_alpha[0] + static_alpha[s * 5 + j])
                            : (th * scale_beta[0]  + static_beta[s]);
    }
    __syncthreads();

    // ---- M[so][si] = beta[so]*alpha[si][0] + alpha[si][so+1] (broadcast reads) ----
    float M[NS][NS];
#pragma unroll
    for (int so = 0; so < NS; ++so)
#pragma unroll
        for (int si = 0; si < NS; ++si)
            M[so][si] = __builtin_fmaf(asb[so][5], asb[si][0], asb[si][so + 1]);

    // ---- Apply: own 2 rows from regs, other 2 from LDS. Branch is wave-uniform;
    //      all register indices literal inside each arm (rule #20). ----
    if (pair == 0) {
        f32x4 y2 = *(const f32x4*)&xex[2][c][0];
        f32x4 y3 = *(const f32x4*)&xex[3][c][0];
#pragma unroll
        for (int so = 0; so < 2; ++so) {
            f32x4 o;
#pragma unroll
            for (int e = 0; e < 4; ++e)
                o[e] = M[so][0] * xA[e] + M[so][1] * xB[e]
                     + M[so][2] * y2[e] + M[so][3] * y3[e];
            __builtin_nontemporal_store(o, (f32x4*)(obase + (size_t)so * row_stride + d));
        }
    } else {
        f32x4 y0 = *(const f32x4*)&xex[0][c][0];
        f32x4 y1 = *(const f32x4*)&xex[1][c][0];
#pragma unroll
        for (int so = 2; so < 4; ++so) {
            f32x4 o;
#pragma unroll
            for (int e = 0; e < 4; ++e)
                o[e] = M[so][0] * y0[e] + M[so][1] * y1[e]
                     + M[so][2] * xA[e] + M[so][3] * xB[e];
            __builtin_nontemporal_store(o, (f32x4*)(obase + (size_t)so * row_stride + d));
        }
    }
}

extern "C" void kernel_launch(void* const* d_in, const int* in_sizes, int n_in,
                              void* d_out, int out_size, void* d_ws, size_t ws_size,
                              hipStream_t stream) {
    const float* residuals    = (const float*)d_in[0];
    const float* gamma        = (const float*)d_in[1];
    const float* w_alpha      = (const float*)d_in[2];
    const float* scale_alpha  = (const float*)d_in[3];
    const float* static_alpha = (const float*)d_in[4];
    const float* w_beta       = (const float*)d_in[5];
    const float* scale_beta   = (const float*)d_in[6];
    const float* static_beta  = (const float*)d_in[7];
    float* out = (float*)d_out;

    const int grid = NB * NN;  // 8192 blocks, one per (b, n)
    hyperconn_kernel<<<grid, NTHREADS, 0, stream>>>(
        residuals, gamma, w_alpha, scale_alpha, static_alpha,
        w_beta, scale_beta, static_beta, out);
}

// Round 12
// 84.715 us; speedup vs baseline: 1.1961x; 1.1961x over previous
//
#include <hip/hip_runtime.h>
#include <math.h>

// Problem shape (fixed by the reference): B=4, S=4, N=2048, D=2048
#define NB 4
#define NS 4
#define NN 2048
#define ND 2048
#define NTHREADS 512
#define KPB 4            // (b,n) pairs per block, software-pipelined
#define SQRT_D 45.254833995939045f   // sqrt(2048)

typedef float f32x4 __attribute__((ext_vector_type(4)));

// Compaction-butterfly ship, literal indices only (R3 lesson, R5/R7/R9-proven).
#define SHIP(I, H, M_) {                                      \
    const float keep_ = hi_ ? v[(I)+(H)] : v[(I)];            \
    const float give_ = hi_ ? v[(I)] : v[(I)+(H)];            \
    v[(I)] = keep_ + __shfl_xor(give_, (M_)); }

#define BUTTERFLY()                                                          \
    { const bool hi_ = (lane & 1) != 0;                                      \
      SHIP(0,16,1)  SHIP(1,16,1)  SHIP(2,16,1)  SHIP(3,16,1)                 \
      SHIP(4,16,1)  SHIP(5,16,1)  SHIP(6,16,1)  SHIP(7,16,1)                 \
      SHIP(8,16,1)  SHIP(9,16,1)  SHIP(10,16,1) SHIP(11,16,1)                \
      SHIP(12,16,1) SHIP(13,16,1) SHIP(14,16,1) SHIP(15,16,1) }              \
    { const bool hi_ = (lane & 2) != 0;                                      \
      SHIP(0,8,2) SHIP(1,8,2) SHIP(2,8,2) SHIP(3,8,2)                        \
      SHIP(4,8,2) SHIP(5,8,2) SHIP(6,8,2) SHIP(7,8,2) }                      \
    { const bool hi_ = (lane & 4) != 0;                                      \
      SHIP(0,4,4) SHIP(1,4,4) SHIP(2,4,4) SHIP(3,4,4) }                      \
    { const bool hi_ = (lane & 8) != 0;                                      \
      SHIP(0,2,8) SHIP(1,2,8) }                                              \
    { const bool hi_ = (lane & 16) != 0;                                     \
      SHIP(0,1,16) }

// One (b,n) iteration. XC0..3 = current x (named f32x4 regs), XN0..3 = next
// x destination. K, PREF literal at every expansion (R3/R9 discipline).
// R10 lesson: the pressure-aware scheduler SINKS the prefetch loads to their
// first use (next iter) unless fenced -> sched_barrier(0) pins the issue
// point before the butterfly; ~1500cy of reduce/epilogue/apply then covers
// the HBM latency. At ~100 VGPR < 128 cap, regalloc has no reason to remat.
#define ITER(XC0, XC1, XC2, XC3, XN0, XN1, XN2, XN3, K, PREF)                \
  {                                                                          \
    float v[32];                                                             \
    _Pragma("unroll") for (int q = 0; q < 32; ++q) v[q] = 0.f;               \
    {                                                                        \
      f32x4 g4 = *(const f32x4*)(gamma + d);                                 \
      _Pragma("unroll") for (int e = 0; e < 4; ++e) {                        \
        v[0]  = __builtin_fmaf(XC0[e], XC0[e], v[0]);                        \
        v[7]  = __builtin_fmaf(XC1[e], XC1[e], v[7]);                        \
        v[14] = __builtin_fmaf(XC2[e], XC2[e], v[14]);                       \
        v[21] = __builtin_fmaf(XC3[e], XC3[e], v[21]);                       \
      }                                                                      \
      _Pragma("unroll") for (int j = 0; j < 6; ++j) {                        \
        const float* wsrc = (j < 5) ? (w_alpha + (size_t)j * ND + d)         \
                                    : (w_beta + d);                          \
        f32x4 w4 = *(const f32x4*)wsrc;                                      \
        f32x4 wg = w4 + w4 * g4;        /* w * (1 + gamma) */                \
        _Pragma("unroll") for (int e = 0; e < 4; ++e) {                      \
          v[1 + j]  = __builtin_fmaf(XC0[e], wg[e], v[1 + j]);               \
          v[8 + j]  = __builtin_fmaf(XC1[e], wg[e], v[8 + j]);               \
          v[15 + j] = __builtin_fmaf(XC2[e], wg[e], v[15 + j]);              \
          v[22 + j] = __builtin_fmaf(XC3[e], wg[e], v[22 + j]);              \
        }                                                                    \
      }                                                                      \
    }                                                                        \
    /* prefetch next bn's x, pinned here by the scheduling fence */          \
    if (PREF) {                                                              \
      const float* np_ = xp + ((K) + 1) * ND;                                \
      XN0 = *(const f32x4*)(np_);                                            \
      XN1 = *(const f32x4*)(np_ + row_stride);                               \
      XN2 = *(const f32x4*)(np_ + 2 * row_stride);                           \
      XN3 = *(const f32x4*)(np_ + 3 * row_stride);                           \
      __builtin_amdgcn_sched_barrier(0);                                     \
    }                                                                        \
    BUTTERFLY()                                                              \
    const float tot##K = v[0] + __shfl_xor(v[0], 32);                        \
    if (lane < 32) red[wave][bidx] = tot##K;                                 \
    __syncthreads();                                                         \
    if (tid < 24) {                                                          \
      const int s_ = tid / 6;                                                \
      const int j_ = tid % 6;                                                \
      float ssq_ = 0.f, dot_ = 0.f;                                          \
      _Pragma("unroll") for (int w = 0; w < 8; ++w) {                        \
        ssq_ += red[w][s_ * 7];                                              \
        dot_ += red[w][s_ * 7 + 1 + j_];                                     \
      }                                                                      \
      const float rs_ = SQRT_D / fmaxf(sqrtf(ssq_), 1e-12f);                 \
      const float th_ = tanhf(dot_ * rs_);                                   \
      asb[s_][j_] = (j_ < 5) ? (th_ * sa + static_alpha[s_ * 5 + j_])        \
                             : (th_ * sb + static_beta[s_]);                 \
    }                                                                        \
    __syncthreads();                                                         \
    {                                                                        \
      float M[NS][NS];                                                       \
      _Pragma("unroll") for (int so = 0; so < NS; ++so)                      \
        _Pragma("unroll") for (int si = 0; si < NS; ++si)                    \
          M[so][si] = __builtin_fmaf(asb[so][5], asb[si][0],                 \
                                     asb[si][so + 1]);                       \
      float* op_ = op + (K) * ND;                                            \
      _Pragma("unroll") for (int so = 0; so < NS; ++so) {                    \
        f32x4 o;                                                             \
        _Pragma("unroll") for (int e = 0; e < 4; ++e)                        \
          o[e] = M[so][0] * XC0[e] + M[so][1] * XC1[e]                       \
               + M[so][2] * XC2[e] + M[so][3] * XC3[e];                      \
        __builtin_nontemporal_store(o, (f32x4*)(op_ + (size_t)so * row_stride)); \
      }                                                                      \
    }                                                                        \
  }

// 512 threads, one f32x4 chunk per thread, 4 bn per block with pinned
// prefetch. Budget: v[32]+xc[16]+xn[16]+temps ~= 100 < 128 cap at (512,4).
__global__ __launch_bounds__(NTHREADS, 4)
void hyperconn_kernel(const float* __restrict__ residuals,
                      const float* __restrict__ gamma,
                      const float* __restrict__ w_alpha,
                      const float* __restrict__ scale_alpha,
                      const float* __restrict__ static_alpha,
                      const float* __restrict__ w_beta,
                      const float* __restrict__ scale_beta,
                      const float* __restrict__ static_beta,
                      float* __restrict__ out)
{
    __shared__ float red[8][32];   // per-wave compacted sums (idx = brev5)
    __shared__ float asb[NS][6];   // [s][0..4]=alpha row, [s][5]=beta

    const int tid  = threadIdx.x;
    const int blk  = blockIdx.x;              // 0 .. 2047
    const int b    = blk >> 9;                // 512 blocks per b
    const int n0   = (blk & 511) * KPB;       // 4 adjacent n
    const int wave = tid >> 6;
    const int lane = tid & 63;
    const int d    = tid << 2;                // one f32x4 chunk per thread

    const size_t row_stride = (size_t)NN * ND;
    const float* xp = residuals + (size_t)(b * NS) * row_stride + (size_t)n0 * ND + d;
    float*       op = out       + (size_t)(b * NS) * row_stride + (size_t)n0 * ND + d;

    const float sa = scale_alpha[0], sb = scale_beta[0];
    const int bidx = ((lane & 1) << 4) | ((lane & 2) << 2) | (lane & 4)
                   | ((lane & 8) >> 2) | ((lane & 16) >> 4);   // brev5(lane&31)

    // Prologue: load bn0's x
    f32x4 a0 = *(const f32x4*)(xp);
    f32x4 a1 = *(const f32x4*)(xp + row_stride);
    f32x4 a2 = *(const f32x4*)(xp + 2 * row_stride);
    f32x4 a3 = *(const f32x4*)(xp + 3 * row_stride);
    f32x4 c0, c1, c2, c3;   // ping-pong partner, filled by prefetch

    ITER(a0, a1, a2, a3, c0, c1, c2, c3, 0, 1)
    ITER(c0, c1, c2, c3, a0, a1, a2, a3, 1, 1)
    ITER(a0, a1, a2, a3, c0, c1, c2, c3, 2, 1)
    ITER(c0, c1, c2, c3, a0, a1, a2, a3, 3, 0)
}

extern "C" void kernel_launch(void* const* d_in, const int* in_sizes, int n_in,
                              void* d_out, int out_size, void* d_ws, size_t ws_size,
                              hipStream_t stream) {
    const float* residuals    = (const float*)d_in[0];
    const float* gamma        = (const float*)d_in[1];
    const float* w_alpha      = (const float*)d_in[2];
    const float* scale_alpha  = (const float*)d_in[3];
    const float* static_alpha = (const float*)d_in[4];
    const float* w_beta       = (const float*)d_in[5];
    const float* scale_beta   = (const float*)d_in[6];
    const float* static_beta  = (const float*)d_in[7];
    float* out = (float*)d_out;

    const int grid = NB * NN / KPB;  // 2048 blocks, 4 bn each
    hyperconn_kernel<<<grid, NTHREADS, 0, stream>>>(
        residuals, gamma, w_alpha, scale_alpha, static_alpha,
        w_beta, scale_beta, static_beta, out);
}

// Round 13
// 84.693 us; speedup vs baseline: 1.1964x; 1.0003x over previous
//
#include <hip/hip_runtime.h>
#include <math.h>

// Problem shape (fixed by the reference): B=4, S=4, N=2048, D=2048
#define NB 4
#define NS 4
#define NN 2048
#define ND 2048
#define NTHREADS 512
#define KPB 4            // (b,n) pairs per block, software-pipelined
#define SQRT_D 45.254833995939045f   // sqrt(2048)

typedef float f32x4 __attribute__((ext_vector_type(4)));

// Pinned prefetch load: asm volatile CANNOT be sunk/CSE'd/remat'd (R10/R12
// lesson: plain loads and sched_barrier-fenced loads both got sunk; VGPR
// dropped to 48/52 and the prefetch silently became a no-op). "=&v" forces
// the destination live from issue to use.
#define GLOAD(dst, addr) \
    asm volatile("global_load_dwordx4 %0, %1, off" : "=&v"(dst) : "v"(addr) : "memory")

// Consume-side fence (rule #18): the asm output LOOKS ready to the compiler,
// so an explicit counted wait + sched_barrier must precede the first use.
// vmcnt(4): the 4 newest outstanding VMEM ops at iter-start are always the
// previous iter's 4 NT stores; everything older (our prefetch loads) drains.
#define VM_WAIT_PREFETCH() do {                                \
    asm volatile("s_waitcnt vmcnt(4)" ::: "memory");           \
    __builtin_amdgcn_sched_barrier(0); } while (0)

// Compaction-butterfly ship, literal indices only (R3 lesson, R5/R7/R9-proven).
#define SHIP(I, H, M_) {                                      \
    const float keep_ = hi_ ? v[(I)+(H)] : v[(I)];            \
    const float give_ = hi_ ? v[(I)] : v[(I)+(H)];            \
    v[(I)] = keep_ + __shfl_xor(give_, (M_)); }

#define BUTTERFLY()                                                          \
    { const bool hi_ = (lane & 1) != 0;                                      \
      SHIP(0,16,1)  SHIP(1,16,1)  SHIP(2,16,1)  SHIP(3,16,1)                 \
      SHIP(4,16,1)  SHIP(5,16,1)  SHIP(6,16,1)  SHIP(7,16,1)                 \
      SHIP(8,16,1)  SHIP(9,16,1)  SHIP(10,16,1) SHIP(11,16,1)                \
      SHIP(12,16,1) SHIP(13,16,1) SHIP(14,16,1) SHIP(15,16,1) }              \
    { const bool hi_ = (lane & 2) != 0;                                      \
      SHIP(0,8,2) SHIP(1,8,2) SHIP(2,8,2) SHIP(3,8,2)                        \
      SHIP(4,8,2) SHIP(5,8,2) SHIP(6,8,2) SHIP(7,8,2) }                      \
    { const bool hi_ = (lane & 4) != 0;                                      \
      SHIP(0,4,4) SHIP(1,4,4) SHIP(2,4,4) SHIP(3,4,4) }                      \
    { const bool hi_ = (lane & 8) != 0;                                      \
      SHIP(0,2,8) SHIP(1,2,8) }                                              \
    { const bool hi_ = (lane & 16) != 0;                                     \
      SHIP(0,1,16) }

// One (b,n) iteration. XC0..3 = current x, XN0..3 = prefetch destination.
// K / PREF / WAIT are literals at every expansion (R3/R9 discipline).
// No compiler VMEM between the GLOADs and the stores (stat/sa/sb hoisted)
// so the vmcnt(4) count stays exact.
#define ITER(XC0, XC1, XC2, XC3, XN0, XN1, XN2, XN3, K, PREF, WAIT)          \
  {                                                                          \
    if (WAIT) VM_WAIT_PREFETCH();                                            \
    float v[32];                                                             \
    _Pragma("unroll") for (int q = 0; q < 32; ++q) v[q] = 0.f;               \
    {                                                                        \
      f32x4 g4 = *(const f32x4*)(gamma + d);                                 \
      _Pragma("unroll") for (int e = 0; e < 4; ++e) {                        \
        v[0]  = __builtin_fmaf(XC0[e], XC0[e], v[0]);                        \
        v[7]  = __builtin_fmaf(XC1[e], XC1[e], v[7]);                        \
        v[14] = __builtin_fmaf(XC2[e], XC2[e], v[14]);                       \
        v[21] = __builtin_fmaf(XC3[e], XC3[e], v[21]);                       \
      }                                                                      \
      _Pragma("unroll") for (int j = 0; j < 6; ++j) {                        \
        const float* wsrc = (j < 5) ? (w_alpha + (size_t)j * ND + d)         \
                                    : (w_beta + d);                          \
        f32x4 w4 = *(const f32x4*)wsrc;                                      \
        f32x4 wg = w4 + w4 * g4;        /* w * (1 + gamma) */                \
        _Pragma("unroll") for (int e = 0; e < 4; ++e) {                      \
          v[1 + j]  = __builtin_fmaf(XC0[e], wg[e], v[1 + j]);               \
          v[8 + j]  = __builtin_fmaf(XC1[e], wg[e], v[8 + j]);               \
          v[15 + j] = __builtin_fmaf(XC2[e], wg[e], v[15 + j]);              \
          v[22 + j] = __builtin_fmaf(XC3[e], wg[e], v[22 + j]);              \
        }                                                                    \
      }                                                                      \
    }                                                                        \
    /* pinned prefetch: in flight across butterfly+barriers+tanh+apply */    \
    if (PREF) {                                                              \
      const float* np_ = xp + ((K) + 1) * ND;                                \
      GLOAD(XN0, np_);                                                       \
      GLOAD(XN1, np_ + row_stride);                                          \
      GLOAD(XN2, np_ + 2 * row_stride);                                      \
      GLOAD(XN3, np_ + 3 * row_stride);                                      \
    }                                                                        \
    BUTTERFLY()                                                              \
    const float tot##K = v[0] + __shfl_xor(v[0], 32);                        \
    if (lane < 32) red[wave][bidx] = tot##K;                                 \
    __syncthreads();                                                         \
    if (tid < 24) {                                                          \
      float ssq_ = 0.f, dot_ = 0.f;                                          \
      _Pragma("unroll") for (int w = 0; w < 8; ++w) {                        \
        ssq_ += red[w][es * 7];                                              \
        dot_ += red[w][es * 7 + 1 + ej];                                     \
      }                                                                      \
      const float rs_ = SQRT_D / fmaxf(sqrtf(ssq_), 1e-12f);                 \
      asb[es][ej] = __builtin_fmaf(tanhf(dot_ * rs_),                        \
                                   (ej < 5) ? sa : sb, stat);                \
    }                                                                        \
    __syncthreads();                                                         \
    {                                                                        \
      float M[NS][NS];                                                       \
      _Pragma("unroll") for (int so = 0; so < NS; ++so)                      \
        _Pragma("unroll") for (int si = 0; si < NS; ++si)                    \
          M[so][si] = __builtin_fmaf(asb[so][5], asb[si][0],                 \
                                     asb[si][so + 1]);                       \
      float* op_ = op + (K) * ND;                                            \
      _Pragma("unroll") for (int so = 0; so < NS; ++so) {                    \
        f32x4 o;                                                             \
        _Pragma("unroll") for (int e = 0; e < 4; ++e)                        \
          o[e] = M[so][0] * XC0[e] + M[so][1] * XC1[e]                       \
               + M[so][2] * XC2[e] + M[so][3] * XC3[e];                      \
        __builtin_nontemporal_store(o, (f32x4*)(op_ + (size_t)so * row_stride)); \
      }                                                                      \
    }                                                                        \
  }

// 512 threads, one f32x4 chunk per thread, 4 bn per block with asm-pinned
// prefetch. Budget: v[32]+xc[16]+xn[16]+temps ~= 100 < 128 cap at (512,4).
__global__ __launch_bounds__(NTHREADS, 4)
void hyperconn_kernel(const float* __restrict__ residuals,
                      const float* __restrict__ gamma,
                      const float* __restrict__ w_alpha,
                      const float* __restrict__ scale_alpha,
                      const float* __restrict__ static_alpha,
                      const float* __restrict__ w_beta,
                      const float* __restrict__ scale_beta,
                      const float* __restrict__ static_beta,
                      float* __restrict__ out)
{
    __shared__ float red[8][32];   // per-wave compacted sums (idx = brev5)
    __shared__ float asb[NS][6];   // [s][0..4]=alpha row, [s][5]=beta

    const int tid  = threadIdx.x;
    const int blk  = blockIdx.x;              // 0 .. 2047
    const int b    = blk >> 9;                // 512 blocks per b
    const int n0   = (blk & 511) * KPB;       // 4 adjacent n
    const int wave = tid >> 6;
    const int lane = tid & 63;
    const int d    = tid << 2;                // one f32x4 chunk per thread

    const size_t row_stride = (size_t)NN * ND;
    const float* xp = residuals + (size_t)(b * NS) * row_stride + (size_t)n0 * ND + d;
    float*       op = out       + (size_t)(b * NS) * row_stride + (size_t)n0 * ND + d;

    // Hoisted epilogue constants: NO compiler VMEM inside the iter body
    // between prefetch issue and the NT stores (keeps vmcnt(4) exact).
    const float sa = scale_alpha[0], sb = scale_beta[0];
    const int t24 = (tid < 24) ? tid : 0;
    const int es = t24 / 6, ej = t24 % 6;
    const float stat = (ej < 5) ? static_alpha[es * 5 + ej] : static_beta[es];
    const int bidx = ((lane & 1) << 4) | ((lane & 2) << 2) | (lane & 4)
                   | ((lane & 8) >> 2) | ((lane & 16) >> 4);   // brev5(lane&31)

    // Prologue: load bn0's x (compiler-scheduled; consumed immediately)
    f32x4 a0 = *(const f32x4*)(xp);
    f32x4 a1 = *(const f32x4*)(xp + row_stride);
    f32x4 a2 = *(const f32x4*)(xp + 2 * row_stride);
    f32x4 a3 = *(const f32x4*)(xp + 3 * row_stride);
    f32x4 c0, c1, c2, c3;   // ping-pong partner, filled by pinned prefetch

    ITER(a0, a1, a2, a3, c0, c1, c2, c3, 0, 1, 0)
    ITER(c0, c1, c2, c3, a0, a1, a2, a3, 1, 1, 1)
    ITER(a0, a1, a2, a3, c0, c1, c2, c3, 2, 1, 1)
    ITER(c0, c1, c2, c3, a0, a1, a2, a3, 3, 0, 1)
}

extern "C" void kernel_launch(void* const* d_in, const int* in_sizes, int n_in,
                              void* d_out, int out_size, void* d_ws, size_t ws_size,
                              hipStream_t stream) {
    const float* residuals    = (const float*)d_in[0];
    const float* gamma        = (const float*)d_in[1];
    const float* w_alpha      = (const float*)d_in[2];
    const float* scale_alpha  = (const float*)d_in[3];
    const float* static_alpha = (const float*)d_in[4];
    const float* w_beta       = (const float*)d_in[5];
    const float* scale_beta   = (const float*)d_in[6];
    const float* static_beta  = (const float*)d_in[7];
    float* out = (float*)d_out;

    const int grid = NB * NN / KPB;  // 2048 blocks, 4 bn each
    hyperconn_kernel<<<grid, NTHREADS, 0, stream>>>(
        residuals, gamma, w_alpha, scale_alpha, static_alpha,
        w_beta, scale_beta, static_beta, out);
}